// Round 12
// baseline (528.497 us; speedup 1.0000x reference)
//
#include <hip/hip_runtime.h>

typedef __attribute__((ext_vector_type(8))) short bf16x8;
typedef __attribute__((ext_vector_type(4))) float f32x4;
typedef __attribute__((ext_vector_type(4))) unsigned short us4;
typedef __attribute__((ext_vector_type(8))) unsigned short us8;

#define NROWS 262144
#define KC 256
#define DD 256
#define BM 128       // rows per block (32 per wave)
#define DK 32        // D-chunk (= one MFMA K)
#define TAU 1.5e-3f  // flag threshold: ~9 sigma of single-pass bf16 error + np fp32 rounding
#define FCAP 65536   // flag list capacity

// ===== bit-exact numpy emulation helpers (defeat -ffp-contract) =====
__device__ __forceinline__ float np_pw128_sq(const float* a) {
    float r[8];
#pragma unroll
    for (int j = 0; j < 8; ++j) r[j] = __fmul_rn(a[j], a[j]);
    for (int i = 8; i < 128; i += 8) {
#pragma unroll
        for (int j = 0; j < 8; ++j)
            r[j] = __fadd_rn(r[j], __fmul_rn(a[i + j], a[i + j]));
    }
    float t01 = __fadd_rn(r[0], r[1]), t23 = __fadd_rn(r[2], r[3]);
    float t45 = __fadd_rn(r[4], r[5]), t67 = __fadd_rn(r[6], r[7]);
    return __fadd_rn(__fadd_rn(t01, t23), __fadd_rn(t45, t67));
}
__device__ __forceinline__ float np_sum256_sq(const float* a) {
    return __fadd_rn(np_pw128_sq(a), np_pw128_sq(a + 128));
}

// bf16 round-to-nearest-even
__device__ __forceinline__ unsigned short bf16_rne(float x) {
    unsigned b = __float_as_uint(x);
    b += 0x7FFFu + ((b >> 16) & 1u);
    return (unsigned short)(b >> 16);
}

// ---------- prep: se[k] = np-bit-exact sum(emb[k]^2); zero accum + flag count ----------
__global__ void vq_prep(const float* __restrict__ emb, float* __restrict__ se,
                        double* __restrict__ accum, int* __restrict__ gcnt) {
    int k = threadIdx.x;
    if (k == 0) { *accum = 0.0; *gcnt = 0; }
    se[k] = np_sum256_sq(emb + (size_t)k * DD);
}

// ---------- split emb -> dc-tiled bf16 (RNE) plane: plane[tile][k][32] ----------
__global__ void vq_split(const float* __restrict__ emb, unsigned short* __restrict__ ph) {
    int f = (blockIdx.x * 256 + threadIdx.x) * 4;   // element index
    float4 v = *reinterpret_cast<const float4*>(emb + f);
    int k = f >> 8, d = f & 255;
    int off = (d >> 5) * (KC * DK) + k * DK + (d & 31);
    us4 h;
    h[0] = bf16_rne(v.x); h[1] = bf16_rne(v.y);
    h[2] = bf16_rne(v.z); h[3] = bf16_rne(v.w);
    *reinterpret_cast<us4*>(ph + off) = h;
}

// ---------- main: wave = 32 rows x 256 codes; z in regs, e direct from L2, no K-loop barriers ----------
__global__ __launch_bounds__(256, 2)
void vq_main(const float* __restrict__ ze, const float* __restrict__ emb,
             const unsigned short* __restrict__ ph,
             const float* __restrict__ se_g, float* __restrict__ out_zq,
             float* __restrict__ out_inds, double* __restrict__ accum,
             int* __restrict__ glist, int* __restrict__ gcnt)
{
    __shared__ float se_s[KC];
    __shared__ int   inds_s[BM];
    __shared__ float red[256];

    const int t = threadIdx.x;
    const int w = t >> 6;          // wave: rows [32w, 32w+32)
    const int l = t & 63;
    const int q = (t >> 4) & 3;    // k-quad within frag
    const int c = t & 15;          // A-row / B-col within frag
    const size_t m0 = (size_t)blockIdx.x * BM;

    se_s[t] = se_g[t];
    __syncthreads();   // se_s visible to ALL waves before any argmin read (r11 bug: this was missing)

    // ---- z: load + convert both row-sets, one chunk at a time (low transients) ----
    const float* zr0 = ze + (m0 + 32 * w + c) * DD + q * 8;
    const float* zr1 = ze + (m0 + 32 * w + 16 + c) * DD + q * 8;
    float sz_acc = 0.f;
    bf16x8 af0[8], af1[8];
#pragma unroll
    for (int dci = 0; dci < 8; ++dci) {
        float4 a0 = *reinterpret_cast<const float4*>(zr0 + dci * 32);
        float4 b0 = *reinterpret_cast<const float4*>(zr0 + dci * 32 + 4);
        float4 a1 = *reinterpret_cast<const float4*>(zr1 + dci * 32);
        float4 b1 = *reinterpret_cast<const float4*>(zr1 + dci * 32 + 4);
        sz_acc = fmaf(a0.x, a0.x, sz_acc); sz_acc = fmaf(a0.y, a0.y, sz_acc);
        sz_acc = fmaf(a0.z, a0.z, sz_acc); sz_acc = fmaf(a0.w, a0.w, sz_acc);
        sz_acc = fmaf(b0.x, b0.x, sz_acc); sz_acc = fmaf(b0.y, b0.y, sz_acc);
        sz_acc = fmaf(b0.z, b0.z, sz_acc); sz_acc = fmaf(b0.w, b0.w, sz_acc);
        sz_acc = fmaf(a1.x, a1.x, sz_acc); sz_acc = fmaf(a1.y, a1.y, sz_acc);
        sz_acc = fmaf(a1.z, a1.z, sz_acc); sz_acc = fmaf(a1.w, a1.w, sz_acc);
        sz_acc = fmaf(b1.x, b1.x, sz_acc); sz_acc = fmaf(b1.y, b1.y, sz_acc);
        sz_acc = fmaf(b1.z, b1.z, sz_acc); sz_acc = fmaf(b1.w, b1.w, sz_acc);
        us8 h0, h1;
        h0[0] = bf16_rne(a0.x); h0[1] = bf16_rne(a0.y); h0[2] = bf16_rne(a0.z); h0[3] = bf16_rne(a0.w);
        h0[4] = bf16_rne(b0.x); h0[5] = bf16_rne(b0.y); h0[6] = bf16_rne(b0.z); h0[7] = bf16_rne(b0.w);
        h1[0] = bf16_rne(a1.x); h1[1] = bf16_rne(a1.y); h1[2] = bf16_rne(a1.z); h1[3] = bf16_rne(a1.w);
        h1[4] = bf16_rne(b1.x); h1[5] = bf16_rne(b1.y); h1[6] = bf16_rne(b1.z); h1[7] = bf16_rne(b1.w);
        af0[dci] = __builtin_bit_cast(bf16x8, h0);
        af1[dci] = __builtin_bit_cast(bf16x8, h1);
    }

    f32x4 acc0[16], acc1[16];
#pragma unroll
    for (int i = 0; i < 16; ++i) {
        acc0[i] = (f32x4){0.f, 0.f, 0.f, 0.f};
        acc1[i] = (f32x4){0.f, 0.f, 0.f, 0.f};
    }

    // ---- K-loop: B-frags straight from L2-hot plane (contiguous 1KB per wave-inst), no sync ----
#pragma unroll
    for (int dci = 0; dci < 8; ++dci) {
        const unsigned short* ep = ph + dci * (KC * DK) + c * DK + q * 8;
#pragma unroll
        for (int nf = 0; nf < 16; ++nf) {
            bf16x8 b = *reinterpret_cast<const bf16x8*>(ep + nf * 16 * DK);
            acc0[nf] = __builtin_amdgcn_mfma_f32_16x16x32_bf16(af0[dci], b, acc0[nf], 0, 0, 0);
            acc1[nf] = __builtin_amdgcn_mfma_f32_16x16x32_bf16(af1[dci], b, acc1[nf], 0, 0, 0);
        }
    }

    // ---- per-row argmin, fully wave-local; row = 32w + 16s + 4q + j, code = 16nf + c ----
    float lossv = 0.f;
#define ARGMIN_SET(ACC, S)                                                     \
    {                                                                          \
        _Pragma("unroll")                                                      \
        for (int j = 0; j < 4; ++j) {                                          \
            float v1 = 3.4e38f, v2 = 3.4e38f; int k1 = 0x7fffffff;             \
            _Pragma("unroll")                                                  \
            for (int nf = 0; nf < 16; ++nf) {                                  \
                int k = 16 * nf + c;                                           \
                float dv = fmaf(-2.f, ACC[nf][j], se_s[k]);                    \
                if (dv < v1) { v2 = v1; v1 = dv; k1 = k; }                     \
                else if (dv < v2) { v2 = dv; }                                 \
            }                                                                  \
            _Pragma("unroll")                                                  \
            for (int off = 1; off < 16; off <<= 1) {                           \
                float ov1 = __shfl_xor(v1, off, 64);                           \
                float ov2 = __shfl_xor(v2, off, 64);                           \
                int   ok1 = __shfl_xor(k1, off, 64);                           \
                bool other = (ov1 < v1) || (ov1 == v1 && ok1 < k1);            \
                float nv2 = other ? fminf(v1, ov2) : fminf(v2, ov1);           \
                if (other) { v1 = ov1; k1 = ok1; }                             \
                v2 = nv2;                                                      \
            }                                                                  \
            if (c == 0) {                                                      \
                int row = 32 * w + 16 * (S) + 4 * q + j;                       \
                inds_s[row] = k1;                                              \
                lossv += v1;                                                   \
                if (v2 - v1 < TAU) {                                           \
                    int s_ = atomicAdd(gcnt, 1);                               \
                    if (s_ < FCAP) glist[s_] = (int)(m0 + row);                \
                }                                                              \
            }                                                                  \
        }                                                                      \
    }
    ARGMIN_SET(acc0, 0)
    ARGMIN_SET(acc1, 1)
#undef ARGMIN_SET
    __syncthreads();

    // ---- write indices (as float) ----
    if (t < BM) out_inds[m0 + t] = (float)inds_s[t];

    // ---- gather + write z_q: wave writes its 32 rows, 1 KB per instruction ----
#pragma unroll 4
    for (int r = 0; r < 32; ++r) {
        int k = inds_s[32 * w + r];
        float4 v = *reinterpret_cast<const float4*>(emb + (size_t)k * DD + l * 4);
        *reinterpret_cast<float4*>(out_zq + (m0 + 32 * w + r) * DD + l * 4) = v;
    }

    // ---- loss partial ----
    red[t] = sz_acc + lossv;
    __syncthreads();
    for (int s = 128; s > 0; s >>= 1) {
        if (t < s) red[t] += red[t + s];
        __syncthreads();
    }
    if (t == 0) atomicAdd(accum, (double)red[0]);
}

// ---------- deferred fix: bit-exact np fp32 pipeline, BATCHED 16 rows/group (r8-proven) ----------
__global__ __launch_bounds__(256)
void vq_fix(const float* __restrict__ ze, const float* __restrict__ emb,
            const float* __restrict__ se_g, const int* __restrict__ glist,
            const int* __restrict__ gcnt, float* __restrict__ out_zq,
            float* __restrict__ out_inds)
{
    __shared__ float dq[16][256];
    __shared__ float srow_s[16];
    __shared__ int   rowid_s[16];
    __shared__ int   klds[16];

    const int t = threadIdx.x;
    int F = *gcnt; if (F > FCAP) F = FCAP;
    const float se_k = se_g[t];
    const float4* e4p = reinterpret_cast<const float4*>(emb + (size_t)t * DD);

    for (int g = blockIdx.x * 16; g < F; g += gridDim.x * 16) {
        __syncthreads();   // protect LDS reuse across iterations
        if (t < 16) {
            int idx = g + t; if (idx > F - 1) idx = F - 1;   // pad tail with dup of last
            int row = glist[idx];
            rowid_s[t] = row;
            srow_s[t] = np_sum256_sq(ze + (size_t)row * DD);
        }
        __syncthreads();

        // wave-uniform z-row pointers (scalar loads)
        const float* zp[16];
#pragma unroll
        for (int r = 0; r < 16; ++r)
            zp[r] = ze + (size_t)__builtin_amdgcn_readfirstlane(rowid_s[r]) * DD;

        // thread t emulates code k=t for all 16 rows: sequential 1-acc FMA over d
        float m32[16];
#pragma unroll
        for (int r = 0; r < 16; ++r) m32[r] = 0.f;
        for (int d4 = 0; d4 < 64; ++d4) {
            float4 e4 = e4p[d4];
            const int d = d4 * 4;
#pragma unroll
            for (int r = 0; r < 16; ++r) {
                m32[r] = __fmaf_rn(zp[r][d + 0], e4.x, m32[r]);
                m32[r] = __fmaf_rn(zp[r][d + 1], e4.y, m32[r]);
                m32[r] = __fmaf_rn(zp[r][d + 2], e4.z, m32[r]);
                m32[r] = __fmaf_rn(zp[r][d + 3], e4.w, m32[r]);
            }
        }
#pragma unroll
        for (int r = 0; r < 16; ++r) {
            float A = __fadd_rn(srow_s[r], se_k);
            dq[r][t] = __fsub_rn(A, __fmul_rn(2.0f, m32[r]));
        }
        __syncthreads();

        // per-row argmin: 16 threads per row (r = t>>4, portion p = t&15)
        {
            const int r = t >> 4, p = t & 15;
            float bv = 3.4e38f; int bk = 0x7fffffff;
#pragma unroll
            for (int i = 0; i < 16; ++i) {
                int k = p * 16 + i;
                float v = dq[r][k];
                if (v < bv) { bv = v; bk = k; }   // strict <: lowest index in subset
            }
#pragma unroll
            for (int off = 1; off < 16; off <<= 1) {
                float ov = __shfl_xor(bv, off, 64);
                int   ok = __shfl_xor(bk, off, 64);
                if (ov < bv || (ov == bv && ok < bk)) { bv = ov; bk = ok; }
            }
            if (p == 0) klds[r] = bk;
        }
        __syncthreads();

        int R = F - g; if (R > 16) R = 16;
#pragma unroll
        for (int r = 0; r < 16; ++r) {
            if (r < R) {
                int row = rowid_s[r];
                int kk  = klds[r];
                out_zq[(size_t)row * DD + t] = emb[(size_t)kk * DD + t];
                if (t == 0) out_inds[row] = (float)kk;
            }
        }
    }
}

// ---------- finalize: loss = (1 + 0.25) * mean((z - q)^2) ----------
__global__ void vq_fin(const double* __restrict__ accum, float* __restrict__ out_loss) {
    *out_loss = (float)(1.25 * (*accum) / ((double)NROWS * (double)DD));
}

extern "C" void kernel_launch(void* const* d_in, const int* in_sizes, int n_in,
                              void* d_out, int out_size, void* d_ws, size_t ws_size,
                              hipStream_t stream) {
    const float* ze  = (const float*)d_in[0];
    const float* emb = (const float*)d_in[1];
    float* out      = (float*)d_out;
    float* out_zq   = out;
    float* out_inds = out + (size_t)NROWS * DD;
    float* out_loss = out + (size_t)NROWS * DD + NROWS;

    double* accum = (double*)d_ws;                                   // @0, 8B
    int*    gcnt  = (int*)((char*)d_ws + 8);                         // @8, 4B
    float*  se    = (float*)((char*)d_ws + 256);                     // @256, 1KB
    int*    glist = (int*)((char*)d_ws + 4096);                      // @4K, 256KB
    unsigned short* ph = (unsigned short*)((char*)d_ws + 4096 + 262144);  // 128KB

    vq_prep<<<1, 256, 0, stream>>>(emb, se, accum, gcnt);
    vq_split<<<KC * DD / (256 * 4), 256, 0, stream>>>(emb, ph);
    vq_main<<<NROWS / BM, 256, 0, stream>>>(ze, emb, ph, se, out_zq, out_inds,
                                            accum, glist, gcnt);
    vq_fix<<<1024, 256, 0, stream>>>(ze, emb, se, glist, gcnt, out_zq, out_inds);
    vq_fin<<<1, 1, 0, stream>>>(accum, out_loss);
}

// Round 13
// 347.642 us; speedup vs baseline: 1.5202x; 1.5202x over previous
//
#include <hip/hip_runtime.h>

typedef __attribute__((ext_vector_type(8))) short bf16x8;
typedef __attribute__((ext_vector_type(4))) float f32x4;
typedef __attribute__((ext_vector_type(4))) unsigned short us4;
typedef __attribute__((ext_vector_type(8))) unsigned short us8;

#define NROWS 262144
#define KC 256
#define DD 256
#define BM 128       // rows per block (8 steps x 16 rows)
#define DK 32        // D-chunk (= one MFMA K)
#define TAU 1.5e-3f  // flag threshold: ~9 sigma of single-pass bf16 error + np fp32 rounding
#define FCAP 65536   // flag list capacity

// ===== bit-exact numpy emulation helpers (defeat -ffp-contract) =====
__device__ __forceinline__ float np_pw128_sq(const float* a) {
    float r[8];
#pragma unroll
    for (int j = 0; j < 8; ++j) r[j] = __fmul_rn(a[j], a[j]);
    for (int i = 8; i < 128; i += 8) {
#pragma unroll
        for (int j = 0; j < 8; ++j)
            r[j] = __fadd_rn(r[j], __fmul_rn(a[i + j], a[i + j]));
    }
    float t01 = __fadd_rn(r[0], r[1]), t23 = __fadd_rn(r[2], r[3]);
    float t45 = __fadd_rn(r[4], r[5]), t67 = __fadd_rn(r[6], r[7]);
    return __fadd_rn(__fadd_rn(t01, t23), __fadd_rn(t45, t67));
}
__device__ __forceinline__ float np_sum256_sq(const float* a) {
    return __fadd_rn(np_pw128_sq(a), np_pw128_sq(a + 128));
}

// bf16 round-to-nearest-even
__device__ __forceinline__ unsigned short bf16_rne(float x) {
    unsigned b = __float_as_uint(x);
    b += 0x7FFFu + ((b >> 16) & 1u);
    return (unsigned short)(b >> 16);
}

// ---------- prep: se[k] = np-bit-exact sum(emb[k]^2); zero accum + flag count ----------
__global__ void vq_prep(const float* __restrict__ emb, float* __restrict__ se,
                        double* __restrict__ accum, int* __restrict__ gcnt) {
    int k = threadIdx.x;
    if (k == 0) { *accum = 0.0; *gcnt = 0; }
    se[k] = np_sum256_sq(emb + (size_t)k * DD);
}

// ---------- split emb -> dc-tiled bf16 (RNE) plane: plane[tile][k][32] ----------
__global__ void vq_split(const float* __restrict__ emb, unsigned short* __restrict__ ph) {
    int f = (blockIdx.x * 256 + threadIdx.x) * 4;   // element index
    float4 v = *reinterpret_cast<const float4*>(emb + f);
    int k = f >> 8, d = f & 255;
    int off = (d >> 5) * (KC * DK) + k * DK + (d & 31);
    us4 h;
    h[0] = bf16_rne(v.x); h[1] = bf16_rne(v.y);
    h[2] = bf16_rne(v.z); h[3] = bf16_rne(v.w);
    *reinterpret_cast<us4*>(ph + off) = h;
}

// ---------- main: persistent-B argmin. Wave holds 64 codes in regs; z streams; inds+loss out ----------
__global__ __launch_bounds__(256, 2)
void vq_main(const float* __restrict__ ze, const unsigned short* __restrict__ ph,
             const float* __restrict__ se_g, float* __restrict__ out_inds,
             double* __restrict__ accum, int* __restrict__ glist, int* __restrict__ gcnt)
{
    __shared__ float se_s[KC];
    __shared__ float wv1[4 * 16], wv2[4 * 16];
    __shared__ int   wk1[4 * 16];
    __shared__ float red[256];

    const int t = threadIdx.x;
    const int w = t >> 6;          // wave: codes [64w, 64w+64)
    const int q = (t >> 4) & 3;    // k-quad within frag
    const int c = t & 15;          // A-row / B-col within frag
    const size_t m0 = (size_t)blockIdx.x * BM;

    se_s[t] = se_g[t];

    // ---- persistent B-frags: wave's 64 codes x 256 d, loaded once (L2-hot plane) ----
    bf16x8 bfr[4][8];   // [nf][dci]
#pragma unroll
    for (int nf = 0; nf < 4; ++nf)
#pragma unroll
        for (int dci = 0; dci < 8; ++dci)
            bfr[nf][dci] = *reinterpret_cast<const bf16x8*>(
                ph + dci * (KC * DK) + (w * 64 + nf * 16 + c) * DK + q * 8);

    __syncthreads();   // se_s visible to all waves before any argmin read

    float sz_run = 0.f, loss_run = 0.f;

    // ---- prologue: z loads for step 0 (lane (c,q): row c, d-slice q*8 of each dci) ----
    float4 z0[8], z1[8];
    {
        const float* zb = ze + (m0 + c) * DD + q * 8;
#pragma unroll
        for (int dci = 0; dci < 8; ++dci) {
            z0[dci] = *reinterpret_cast<const float4*>(zb + dci * 32);
            z1[dci] = *reinterpret_cast<const float4*>(zb + dci * 32 + 4);
        }
    }

    for (int step = 0; step < BM / 16; ++step) {
        // ---- cvt + MFMA (consumes z0/z1) ----
        f32x4 acc[4];
#pragma unroll
        for (int nf = 0; nf < 4; ++nf) acc[nf] = (f32x4){0.f, 0.f, 0.f, 0.f};
#pragma unroll
        for (int dci = 0; dci < 8; ++dci) {
            float4 a = z0[dci], b = z1[dci];
            if (w == 0) {   // sz counted once (wave 0 only)
                sz_run = fmaf(a.x, a.x, sz_run); sz_run = fmaf(a.y, a.y, sz_run);
                sz_run = fmaf(a.z, a.z, sz_run); sz_run = fmaf(a.w, a.w, sz_run);
                sz_run = fmaf(b.x, b.x, sz_run); sz_run = fmaf(b.y, b.y, sz_run);
                sz_run = fmaf(b.z, b.z, sz_run); sz_run = fmaf(b.w, b.w, sz_run);
            }
            us8 h;
            h[0] = bf16_rne(a.x); h[1] = bf16_rne(a.y); h[2] = bf16_rne(a.z); h[3] = bf16_rne(a.w);
            h[4] = bf16_rne(b.x); h[5] = bf16_rne(b.y); h[6] = bf16_rne(b.z); h[7] = bf16_rne(b.w);
            bf16x8 af = __builtin_bit_cast(bf16x8, h);
#pragma unroll
            for (int nf = 0; nf < 4; ++nf)
                acc[nf] = __builtin_amdgcn_mfma_f32_16x16x32_bf16(af, bfr[nf][dci], acc[nf], 0, 0, 0);
        }
        // ---- issue next step's z loads now (regs dead; latency hides under argmin+merge) ----
        if (step < BM / 16 - 1) {
            const float* zb = ze + (m0 + (step + 1) * 16 + c) * DD + q * 8;
#pragma unroll
            for (int dci = 0; dci < 8; ++dci) {
                z0[dci] = *reinterpret_cast<const float4*>(zb + dci * 32);
                z1[dci] = *reinterpret_cast<const float4*>(zb + dci * 32 + 4);
            }
        }

        // ---- wave-local argmin over this wave's 64 codes; row = 4q+j, code = 64w+16nf+c ----
#pragma unroll
        for (int j = 0; j < 4; ++j) {
            float v1 = 3.4e38f, v2 = 3.4e38f; int k1 = 0x7fffffff;
#pragma unroll
            for (int nf = 0; nf < 4; ++nf) {
                int k = 64 * w + 16 * nf + c;
                float dv = fmaf(-2.f, acc[nf][j], se_s[k]);
                if (dv < v1) { v2 = v1; v1 = dv; k1 = k; }
                else if (dv < v2) { v2 = dv; }
            }
#pragma unroll
            for (int off = 1; off < 16; off <<= 1) {
                float ov1 = __shfl_xor(v1, off, 64);
                float ov2 = __shfl_xor(v2, off, 64);
                int   ok1 = __shfl_xor(k1, off, 64);
                bool other = (ov1 < v1) || (ov1 == v1 && ok1 < k1);
                float nv2 = other ? fminf(v1, ov2) : fminf(v2, ov1);
                if (other) { v1 = ov1; k1 = ok1; }
                v2 = nv2;
            }
            if (c == 0) {
                wv1[w * 16 + 4 * q + j] = v1;
                wv2[w * 16 + 4 * q + j] = v2;
                wk1[w * 16 + 4 * q + j] = k1;
            }
        }
        __syncthreads();

        // ---- cross-wave merge (t<16: one row each); ascending w = ascending k (tie rule ok) ----
        if (t < 16) {
            float v1 = wv1[t], v2 = wv2[t]; int k1 = wk1[t];
#pragma unroll
            for (int ww = 1; ww < 4; ++ww) {
                float ov1 = wv1[ww * 16 + t], ov2 = wv2[ww * 16 + t];
                int ok1 = wk1[ww * 16 + t];
                bool other = (ov1 < v1) || (ov1 == v1 && ok1 < k1);
                float nv2 = other ? fminf(v1, ov2) : fminf(v2, ov1);
                if (other) { v1 = ov1; k1 = ok1; }
                v2 = nv2;
            }
            out_inds[m0 + step * 16 + t] = (float)k1;
            loss_run += v1;
            if (v2 - v1 < TAU) {
                int s_ = atomicAdd(gcnt, 1);
                if (s_ < FCAP) glist[s_] = (int)(m0 + step * 16 + t);
            }
        }
        __syncthreads();   // wv reuse next step
    }

    // ---- loss partial: sz (wave-0 lanes) + min-dists (t<16 merge threads) ----
    red[t] = (w == 0 ? sz_run : 0.f) + (t < 16 ? loss_run : 0.f);
    __syncthreads();
    for (int s = 128; s > 0; s >>= 1) {
        if (t < s) red[t] += red[t + s];
        __syncthreads();
    }
    if (t == 0) atomicAdd(accum, (double)red[0]);
}

// ---------- deferred fix: bit-exact np fp32 pipeline, BATCHED 16 rows/group (r8-proven, inds only) ----------
__global__ __launch_bounds__(256)
void vq_fix(const float* __restrict__ ze, const float* __restrict__ emb,
            const float* __restrict__ se_g, const int* __restrict__ glist,
            const int* __restrict__ gcnt, float* __restrict__ out_inds)
{
    __shared__ float dq[16][256];
    __shared__ float srow_s[16];
    __shared__ int   rowid_s[16];

    const int t = threadIdx.x;
    int F = *gcnt; if (F > FCAP) F = FCAP;
    const float se_k = se_g[t];
    const float4* e4p = reinterpret_cast<const float4*>(emb + (size_t)t * DD);

    for (int g = blockIdx.x * 16; g < F; g += gridDim.x * 16) {
        __syncthreads();   // protect LDS reuse across iterations
        if (t < 16) {
            int idx = g + t; if (idx > F - 1) idx = F - 1;   // pad tail with dup of last
            int row = glist[idx];
            rowid_s[t] = row;
            srow_s[t] = np_sum256_sq(ze + (size_t)row * DD);
        }
        __syncthreads();

        // wave-uniform z-row pointers (scalar loads)
        const float* zp[16];
#pragma unroll
        for (int r = 0; r < 16; ++r)
            zp[r] = ze + (size_t)__builtin_amdgcn_readfirstlane(rowid_s[r]) * DD;

        // thread t emulates code k=t for all 16 rows: sequential 1-acc FMA over d
        float m32[16];
#pragma unroll
        for (int r = 0; r < 16; ++r) m32[r] = 0.f;
        for (int d4 = 0; d4 < 64; ++d4) {
            float4 e4 = e4p[d4];
            const int d = d4 * 4;
#pragma unroll
            for (int r = 0; r < 16; ++r) {
                m32[r] = __fmaf_rn(zp[r][d + 0], e4.x, m32[r]);
                m32[r] = __fmaf_rn(zp[r][d + 1], e4.y, m32[r]);
                m32[r] = __fmaf_rn(zp[r][d + 2], e4.z, m32[r]);
                m32[r] = __fmaf_rn(zp[r][d + 3], e4.w, m32[r]);
            }
        }
#pragma unroll
        for (int r = 0; r < 16; ++r) {
            float A = __fadd_rn(srow_s[r], se_k);
            dq[r][t] = __fsub_rn(A, __fmul_rn(2.0f, m32[r]));
        }
        __syncthreads();

        // per-row argmin: 16 threads per row (r = t>>4, portion p = t&15)
        {
            const int r = t >> 4, p = t & 15;
            float bv = 3.4e38f; int bk = 0x7fffffff;
#pragma unroll
            for (int i = 0; i < 16; ++i) {
                int k = p * 16 + i;
                float v = dq[r][k];
                if (v < bv) { bv = v; bk = k; }   // strict <: lowest index in subset
            }
#pragma unroll
            for (int off = 1; off < 16; off <<= 1) {
                float ov = __shfl_xor(bv, off, 64);
                int   ok = __shfl_xor(bk, off, 64);
                if (ov < bv || (ov == bv && ok < bk)) { bv = ov; bk = ok; }
            }
            if (p == 0 && g + r < F) out_inds[rowid_s[r]] = (float)bk;
        }
        __syncthreads();
    }
}

// ---------- gather: z_q[row] = emb[inds[row]] — pure streaming-write kernel ----------
__global__ __launch_bounds__(256)
void vq_gather(const float* __restrict__ emb, const float* __restrict__ out_inds,
               float* __restrict__ out_zq)
{
    const int t = threadIdx.x;
    const int w = t >> 6, l = t & 63;
    const size_t m0 = (size_t)blockIdx.x * 128 + (size_t)w * 32;
#pragma unroll 8
    for (int r = 0; r < 32; ++r) {
        int k = (int)out_inds[m0 + r];
        float4 v = *reinterpret_cast<const float4*>(emb + (size_t)k * DD + l * 4);
        *reinterpret_cast<float4*>(out_zq + (m0 + r) * DD + l * 4) = v;
    }
}

// ---------- finalize: loss = (1 + 0.25) * mean((z - q)^2) ----------
__global__ void vq_fin(const double* __restrict__ accum, float* __restrict__ out_loss) {
    *out_loss = (float)(1.25 * (*accum) / ((double)NROWS * (double)DD));
}

extern "C" void kernel_launch(void* const* d_in, const int* in_sizes, int n_in,
                              void* d_out, int out_size, void* d_ws, size_t ws_size,
                              hipStream_t stream) {
    const float* ze  = (const float*)d_in[0];
    const float* emb = (const float*)d_in[1];
    float* out      = (float*)d_out;
    float* out_zq   = out;
    float* out_inds = out + (size_t)NROWS * DD;
    float* out_loss = out + (size_t)NROWS * DD + NROWS;

    double* accum = (double*)d_ws;                                   // @0, 8B
    int*    gcnt  = (int*)((char*)d_ws + 8);                         // @8, 4B
    float*  se    = (float*)((char*)d_ws + 256);                     // @256, 1KB
    int*    glist = (int*)((char*)d_ws + 4096);                      // @4K, 256KB
    unsigned short* ph = (unsigned short*)((char*)d_ws + 4096 + 262144);  // 128KB

    vq_prep<<<1, 256, 0, stream>>>(emb, se, accum, gcnt);
    vq_split<<<KC * DD / (256 * 4), 256, 0, stream>>>(emb, ph);
    vq_main<<<NROWS / BM, 256, 0, stream>>>(ze, ph, se, out_inds, accum, glist, gcnt);
    vq_fix<<<1024, 256, 0, stream>>>(ze, emb, se, glist, gcnt, out_inds);
    vq_gather<<<NROWS / 128, 256, 0, stream>>>(emb, out_inds, out_zq);
    vq_fin<<<1, 1, 0, stream>>>(accum, out_loss);
}